// Round 6
// baseline (258.931 us; speedup 1.0000x reference)
//
#include <hip/hip_runtime.h>
#include <math.h>

// Tacotron2 location-sensitive attention, fp32.
// B=64 T=2048 E=512 H=128 DL=1024 CC=32 K=31
// out = [context (B*E=32768), weights (B*T=131072)] fp32, concatenated.
// R6 PROBE ROUND: k1 and k3 are idempotent -> launched 3x each to measure
// marginal per-kernel cost from dur_us arithmetic (rocprof top-5 is occluded
// by harness poison fills). Also: enc loads are non-temporal (L3-thrash fix).

#define BB 64
#define TT 2048
#define EE 512
#define HH 128
#define DLL 1024
#define CCC 32
#define KK 31

typedef float f32x4 __attribute__((ext_vector_type(4)));

// ws layout (in floats)
#define WS_FW   0        // fw[128][32]                 -> 4096
#define WS_PL   4096     // pl[64][128]                 -> 8192
#define WS_EN   12288    // energies[64][2048]          -> 131072
#define WS_ST   143360   // stats[64][16][2] (m,s)      -> 2048

// ---------------------------------------------------------------------------
// k0: blocks 0..2047: one wave per (b,h) dot  pl[b][h] = lstm[b]·W_lstm[h]
//     block 2048: fw[h][k] = sum_c W_loc[h][c]*conv_w[c][k]
// ---------------------------------------------------------------------------
__global__ __launch_bounds__(256) void k0_prep(const float* __restrict__ lstm,
                                               const float* __restrict__ Wl,
                                               const float* __restrict__ cw,
                                               const float* __restrict__ Wloc,
                                               float* __restrict__ ws) {
  const int blk = blockIdx.x;
  const int tid = threadIdx.x;
  if (blk < 2048) {
    const int wave = tid >> 6, lane = tid & 63;
    const int wg = blk * 4 + wave;      // 0..8191
    const int b = wg >> 7, h = wg & 127;
    const float4* wr = (const float4*)(Wl + (size_t)h * DLL);
    const float4* lr = (const float4*)(lstm + (size_t)b * DLL);
    float s = 0.f;
#pragma unroll
    for (int m = 0; m < 4; ++m) {
      float4 a = wr[m * 64 + lane];
      float4 c = lr[m * 64 + lane];
      s += a.x * c.x + a.y * c.y + a.z * c.z + a.w * c.w;
    }
#pragma unroll
    for (int m = 1; m < 64; m <<= 1) s += __shfl_xor(s, m, 64);
    if (lane == 0) ws[WS_PL + b * HH + h] = s;
  } else {
    __shared__ __align__(16) float wl_s[HH * CCC];  // 4096
    __shared__ __align__(16) float cw_s[CCC * KK];  // 992
#pragma unroll
    for (int m = 0; m < 4; ++m)
      ((float4*)wl_s)[tid + 256 * m] = ((const float4*)Wloc)[tid + 256 * m];
    if (tid < 248) ((float4*)cw_s)[tid] = ((const float4*)cw)[tid];
    __syncthreads();
    const int h = tid >> 1;
    const int kbase = (tid & 1) * 16;
    const int kn = (tid & 1) ? 15 : 16;
    for (int kk = 0; kk < kn; ++kk) {
      const int k = kbase + kk;
      float s = 0.f;
#pragma unroll
      for (int c = 0; c < CCC; ++c) s += wl_s[h * CCC + c] * cw_s[c * KK + k];
      ws[WS_FW + h * 32 + k] = s;
    }
    if (tid & 1) ws[WS_FW + h * 32 + 31] = 0.f;  // pad
  }
}

// ---------------------------------------------------------------------------
// k1: energies[b][t] = sum_h We[h] * tanh(pl[b][h] + pe[b][t][h] + conv_h)
//     conv_h = sum_k fw[h][k] * aw[b][t+k-15] (zero pad)
// Writes raw energies to ws + per-chunk online softmax stats (m_c, s_c).
// ---------------------------------------------------------------------------
__global__ __launch_bounds__(256) void k1_energies(const float* __restrict__ pe,
                                                   const float* __restrict__ aw,
                                                   const float* __restrict__ We,
                                                   float* __restrict__ ws) {
  const int b = blockIdx.y;
  const int chunk = blockIdx.x;
  const int t0 = chunk * 128;
  const int tid = threadIdx.x;
  const int wave = tid >> 6, lane = tid & 63;

  __shared__ __align__(16) float aw_s[160];  // aw[t0-16 .. t0+143], zero-pad
  if (tid < 160) {
    const int tg = t0 - 16 + tid;
    aw_s[tid] = (tg >= 0 && tg < TT) ? aw[b * TT + tg] : 0.f;
  }

  const int h0 = 2 * lane;
  float fw0[32], fw1[32];
  {
    const float4* f4 = (const float4*)(ws + WS_FW);
#pragma unroll
    for (int m = 0; m < 8; ++m) {
      float4 a = f4[h0 * 8 + m];
      fw0[4 * m + 0] = a.x; fw0[4 * m + 1] = a.y;
      fw0[4 * m + 2] = a.z; fw0[4 * m + 3] = a.w;
      float4 c = f4[h0 * 8 + 8 + m];
      fw1[4 * m + 0] = c.x; fw1[4 * m + 1] = c.y;
      fw1[4 * m + 2] = c.z; fw1[4 * m + 3] = c.w;
    }
  }
  const float2 plv = ((const float2*)(ws + WS_PL + b * HH))[lane];
  const float2 wev = ((const float2*)We)[lane];
  const float2* pe2 = (const float2*)(pe + (size_t)b * TT * HH);

  __syncthreads();

  float om = -3.4e38f, os = 0.f;  // online softmax (per-wave; lanes identical)

  for (int p = 0; p < 8; ++p) {
    const int tq = wave * 32 + p * 4;  // local quad start
    float2 pv[4];
#pragma unroll
    for (int j = 0; j < 4; ++j)
      pv[j] = pe2[(size_t)(t0 + tq + j) * 64 + lane];

    float w[36];
    const float4* a4 = (const float4*)&aw_s[tq];
#pragma unroll
    for (int m = 0; m < 9; ++m) {
      float4 v = a4[m];
      w[4 * m + 0] = v.x; w[4 * m + 1] = v.y;
      w[4 * m + 2] = v.z; w[4 * m + 3] = v.w;
    }

    float a0[4], a1[4];
#pragma unroll
    for (int j = 0; j < 4; ++j) {
      a0[j] = plv.x + pv[j].x;
      a1[j] = plv.y + pv[j].y;
    }
#pragma unroll
    for (int k = 0; k < 31; ++k) {
      const float f0 = fw0[k], f1 = fw1[k];
#pragma unroll
      for (int j = 0; j < 4; ++j) {
        a0[j] = fmaf(f0, w[1 + j + k], a0[j]);
        a1[j] = fmaf(f1, w[1 + j + k], a1[j]);
      }
    }
    float e[4];
#pragma unroll
    for (int j = 0; j < 4; ++j) {
      const float th0 = 1.f - 2.f / (__expf(2.f * a0[j]) + 1.f);
      const float th1 = 1.f - 2.f / (__expf(2.f * a1[j]) + 1.f);
      e[j] = wev.x * th0 + wev.y * th1;
    }
#pragma unroll
    for (int m = 1; m < 64; m <<= 1) {
#pragma unroll
      for (int j = 0; j < 4; ++j) e[j] += __shfl_xor(e[j], m, 64);
    }
    if (lane == 0)
      *(float4*)&ws[WS_EN + b * TT + t0 + tq] = make_float4(e[0], e[1], e[2], e[3]);
    // online softmax update (all lanes hold e[0..3] after butterfly)
    float mq = fmaxf(fmaxf(e[0], e[1]), fmaxf(e[2], e[3]));
    float mn = fmaxf(om, mq);
    os = os * __expf(om - mn) + __expf(e[0] - mn) + __expf(e[1] - mn) +
         __expf(e[2] - mn) + __expf(e[3] - mn);
    om = mn;
  }

  __shared__ float sm[4], ss[4];
  if (lane == 0) { sm[wave] = om; ss[wave] = os; }
  __syncthreads();
  if (tid == 0) {
    const float mb = fmaxf(fmaxf(sm[0], sm[1]), fmaxf(sm[2], sm[3]));
    const float sb = ss[0] * __expf(sm[0] - mb) + ss[1] * __expf(sm[1] - mb) +
                     ss[2] * __expf(sm[2] - mb) + ss[3] * __expf(sm[3] - mb);
    float* st = ws + WS_ST + (b * 16 + chunk) * 2;
    st[0] = mb;
    st[1] = sb;
  }
}

// ---------------------------------------------------------------------------
// k3: block = (e-slice of 32 floats, b), grid (16,64). enc loads NON-TEMPORAL
// (enc streams through L3 once per call; keep L3 for pe/Wl).
// ---------------------------------------------------------------------------
__global__ __launch_bounds__(256) void k3_ctx(const float* __restrict__ enc,
                                              const float* __restrict__ ws,
                                              float* __restrict__ wts,
                                              float* __restrict__ ctx) {
  const int es = blockIdx.x;  // 0..15
  const int b = blockIdx.y;
  const int tid = threadIdx.x;

  // combine chunk stats (redundant per block; 32 floats from L2)
  const float* st = ws + WS_ST + b * 32;
  float mb = -3.4e38f;
#pragma unroll
  for (int c = 0; c < 16; ++c) mb = fmaxf(mb, st[2 * c]);
  float S = 0.f;
#pragma unroll
  for (int c = 0; c < 16; ++c) S += st[2 * c + 1] * __expf(st[2 * c] - mb);
  const float inv = 1.f / S;

  // all 2048 weights into LDS
  __shared__ __align__(16) float w_s[TT];     // 8 KB
  __shared__ __align__(16) float4 red[256];   // 4 KB
  {
    const float4* en4 = (const float4*)(ws + WS_EN + (size_t)b * TT);
#pragma unroll
    for (int j = 0; j < 2; ++j) {
      const float4 e = en4[tid * 2 + j];
      float4 w;
      w.x = __expf(e.x - mb) * inv;
      w.y = __expf(e.y - mb) * inv;
      w.z = __expf(e.z - mb) * inv;
      w.w = __expf(e.w - mb) * inv;
      ((float4*)w_s)[tid * 2 + j] = w;
      if (es == 0) ((float4*)(wts + (size_t)b * TT))[tid * 2 + j] = w;
    }
  }
  __syncthreads();

  // stream enc (non-temporal): lane covers float4 col e4, row-group r0
  const int e4 = (es << 3) | (tid & 7);  // float4 col 0..127
  const int r0 = tid >> 3;               // 0..31
  const f32x4* enc4 = (const f32x4*)(enc + (size_t)b * TT * EE);
  f32x4 a0 = {0.f, 0.f, 0.f, 0.f}, a1 = {0.f, 0.f, 0.f, 0.f};
#pragma unroll 8
  for (int i = 0; i < 64; ++i) {
    const int t = r0 + 32 * i;
    const float w = w_s[t];
    const f32x4 v = __builtin_nontemporal_load(&enc4[(size_t)t * 128 + e4]);
    if (i & 1) a1 += w * v; else a0 += w * v;
  }
  a0 += a1;

  // reduce 32 row-groups (fixed order, deterministic)
  red[tid] = *(const float4*)&a0;
  __syncthreads();
#pragma unroll
  for (int off = 128; off >= 8; off >>= 1) {
    if (tid < off) {
      float4 o = red[tid + off];
      float4 m = red[tid];
      m.x += o.x; m.y += o.y; m.z += o.z; m.w += o.w;
      red[tid] = m;
    }
    __syncthreads();
  }
  if (tid < 8) ((float4*)ctx)[b * 128 + (es << 3) + tid] = red[tid];
}

// ---------------------------------------------------------------------------
extern "C" void kernel_launch(void* const* d_in, const int* in_sizes, int n_in,
                              void* d_out, int out_size, void* d_ws, size_t ws_size,
                              hipStream_t stream) {
  const float* enc  = (const float*)d_in[0];  // [B,T,E]
  const float* pe   = (const float*)d_in[1];  // [B,T,H]
  const float* lstm = (const float*)d_in[2];  // [B,1,DL]
  const float* awc  = (const float*)d_in[3];  // [B,T]
  const float* Wl   = (const float*)d_in[4];  // [H,DL]
  const float* cw   = (const float*)d_in[5];  // [CC,1,K]
  const float* Wloc = (const float*)d_in[6];  // [H,CC]
  const float* We   = (const float*)d_in[7];  // [1,H]

  float* out = (float*)d_out;
  float* ctx = out;            // [B,E]
  float* wts = out + BB * EE;  // [B,T]
  float* ws = (float*)d_ws;

  k0_prep<<<2049, 256, 0, stream>>>(lstm, Wl, cw, Wloc, ws);
  // PROBE: k1 x3, k3 x3 (idempotent; marginal cost = per-kernel time).
  k1_energies<<<dim3(16, BB), 256, 0, stream>>>(pe, awc, We, ws);
  k1_energies<<<dim3(16, BB), 256, 0, stream>>>(pe, awc, We, ws);
  k1_energies<<<dim3(16, BB), 256, 0, stream>>>(pe, awc, We, ws);
  k3_ctx<<<dim3(16, BB), 256, 0, stream>>>(enc, ws, wts, ctx);
  k3_ctx<<<dim3(16, BB), 256, 0, stream>>>(enc, ws, wts, ctx);
  k3_ctx<<<dim3(16, BB), 256, 0, stream>>>(enc, ws, wts, ctx);
}

// Round 7
// 87.662 us; speedup vs baseline: 2.9538x; 2.9538x over previous
//
#include <hip/hip_runtime.h>
#include <math.h>

// Tacotron2 location-sensitive attention, fp32.
// B=64 T=2048 E=512 H=128 DL=1024 CC=32 K=31
// out = [context (B*E=32768), weights (B*T=131072)] fp32, concatenated.
// R7: flash-style fusion. k1 computes chunk energies AND streams the chunk's
// enc rows into an unnormalized partial context (exp(e - m_chunk) weights).
// k2 combines 16 chunk partials per b (fixed order) + writes weights.
// Heavy BW (enc 268MB + pe 67MB) now lives in ONE 1024-block dispatch.

#define BB 64
#define TT 2048
#define EE 512
#define HH 128
#define DLL 1024
#define CCC 32
#define KK 31

// ws layout (in floats)
#define WS_FW   0        // fw[128][32]                 -> 4096
#define WS_PL   4096     // pl[64][128]                 -> 8192
#define WS_EN   12288    // energies[64][2048]          -> 131072
#define WS_ST   143360   // stats[64][16][2] (m,s)      -> 2048
#define WS_PART 145472   // partials[64][16][512]       -> 524288

// ---------------------------------------------------------------------------
// k0: blocks 0..2047: one wave per (b,h) dot  pl[b][h] = lstm[b]·W_lstm[h]
//     block 2048: fw[h][k] = sum_c W_loc[h][c]*conv_w[c][k]
// ---------------------------------------------------------------------------
__global__ __launch_bounds__(256) void k0_prep(const float* __restrict__ lstm,
                                               const float* __restrict__ Wl,
                                               const float* __restrict__ cw,
                                               const float* __restrict__ Wloc,
                                               float* __restrict__ ws) {
  const int blk = blockIdx.x;
  const int tid = threadIdx.x;
  if (blk < 2048) {
    const int wave = tid >> 6, lane = tid & 63;
    const int wg = blk * 4 + wave;      // 0..8191
    const int b = wg >> 7, h = wg & 127;
    const float4* wr = (const float4*)(Wl + (size_t)h * DLL);
    const float4* lr = (const float4*)(lstm + (size_t)b * DLL);
    float s = 0.f;
#pragma unroll
    for (int m = 0; m < 4; ++m) {
      float4 a = wr[m * 64 + lane];
      float4 c = lr[m * 64 + lane];
      s += a.x * c.x + a.y * c.y + a.z * c.z + a.w * c.w;
    }
#pragma unroll
    for (int m = 1; m < 64; m <<= 1) s += __shfl_xor(s, m, 64);
    if (lane == 0) ws[WS_PL + b * HH + h] = s;
  } else {
    __shared__ __align__(16) float wl_s[HH * CCC];  // 4096
    __shared__ __align__(16) float cw_s[CCC * KK];  // 992
#pragma unroll
    for (int m = 0; m < 4; ++m)
      ((float4*)wl_s)[tid + 256 * m] = ((const float4*)Wloc)[tid + 256 * m];
    if (tid < 248) ((float4*)cw_s)[tid] = ((const float4*)cw)[tid];
    __syncthreads();
    const int h = tid >> 1;
    const int kbase = (tid & 1) * 16;
    const int kn = (tid & 1) ? 15 : 16;
    for (int kk = 0; kk < kn; ++kk) {
      const int k = kbase + kk;
      float s = 0.f;
#pragma unroll
      for (int c = 0; c < CCC; ++c) s += wl_s[h * CCC + c] * cw_s[c * KK + k];
      ws[WS_FW + h * 32 + k] = s;
    }
    if (tid & 1) ws[WS_FW + h * 32 + 31] = 0.f;  // pad
  }
}

// ---------------------------------------------------------------------------
// k1_fused: per (chunk of 128 t, b):
//  A) energies e_t (conv fused via fw; tanh; We-dot) -> LDS + ws;
//     per-chunk online softmax stats (m_c, s_c) -> ws.
//  B) partial[b][chunk][e] = sum_t exp(e_t - m_c) * enc[b][t][e] -> ws.
// grid (16, 64) = 1024 blocks.
// ---------------------------------------------------------------------------
__global__ __launch_bounds__(256) void k1_fused(const float* __restrict__ pe,
                                                const float* __restrict__ aw,
                                                const float* __restrict__ We,
                                                const float* __restrict__ enc,
                                                float* __restrict__ ws) {
  const int b = blockIdx.y;
  const int chunk = blockIdx.x;
  const int t0 = chunk * 128;
  const int tid = threadIdx.x;
  const int wave = tid >> 6, lane = tid & 63;

  __shared__ __align__(16) float aw_s[160];   // aw[t0-16 .. t0+143], zero-pad
  __shared__ __align__(16) float e_s[128];    // raw energies for this chunk
  __shared__ __align__(16) float w_chunk[128];// exp(e - m_c)
  __shared__ __align__(16) float4 acc_s[128];
  __shared__ float sm[4], ss[4], mb_s;

  if (tid < 160) {
    const int tg = t0 - 16 + tid;
    aw_s[tid] = (tg >= 0 && tg < TT) ? aw[b * TT + tg] : 0.f;
  }

  const int h0 = 2 * lane;
  float fw0[32], fw1[32];
  {
    const float4* f4 = (const float4*)(ws + WS_FW);
#pragma unroll
    for (int m = 0; m < 8; ++m) {
      float4 a = f4[h0 * 8 + m];
      fw0[4 * m + 0] = a.x; fw0[4 * m + 1] = a.y;
      fw0[4 * m + 2] = a.z; fw0[4 * m + 3] = a.w;
      float4 c = f4[h0 * 8 + 8 + m];
      fw1[4 * m + 0] = c.x; fw1[4 * m + 1] = c.y;
      fw1[4 * m + 2] = c.z; fw1[4 * m + 3] = c.w;
    }
  }
  const float2 plv = ((const float2*)(ws + WS_PL + b * HH))[lane];
  const float2 wev = ((const float2*)We)[lane];
  const float2* pe2 = (const float2*)(pe + (size_t)b * TT * HH);

  __syncthreads();

  float om = -3.4e38f, os = 0.f;  // per-wave online softmax (lanes identical)

  for (int p = 0; p < 8; ++p) {
    const int tq = wave * 32 + p * 4;  // local quad start
    float2 pv[4];
#pragma unroll
    for (int j = 0; j < 4; ++j)
      pv[j] = pe2[(size_t)(t0 + tq + j) * 64 + lane];

    float w[36];
    const float4* a4 = (const float4*)&aw_s[tq];
#pragma unroll
    for (int m = 0; m < 9; ++m) {
      float4 v = a4[m];
      w[4 * m + 0] = v.x; w[4 * m + 1] = v.y;
      w[4 * m + 2] = v.z; w[4 * m + 3] = v.w;
    }

    float a0[4], a1[4];
#pragma unroll
    for (int j = 0; j < 4; ++j) {
      a0[j] = plv.x + pv[j].x;
      a1[j] = plv.y + pv[j].y;
    }
#pragma unroll
    for (int k = 0; k < 31; ++k) {
      const float f0 = fw0[k], f1 = fw1[k];
#pragma unroll
      for (int j = 0; j < 4; ++j) {
        a0[j] = fmaf(f0, w[1 + j + k], a0[j]);
        a1[j] = fmaf(f1, w[1 + j + k], a1[j]);
      }
    }
    float e[4];
#pragma unroll
    for (int j = 0; j < 4; ++j) {
      const float th0 = 1.f - 2.f / (__expf(2.f * a0[j]) + 1.f);
      const float th1 = 1.f - 2.f / (__expf(2.f * a1[j]) + 1.f);
      e[j] = wev.x * th0 + wev.y * th1;
    }
#pragma unroll
    for (int m = 1; m < 64; m <<= 1) {
#pragma unroll
      for (int j = 0; j < 4; ++j) e[j] += __shfl_xor(e[j], m, 64);
    }
    if (lane == 0) {
      const float4 ev = make_float4(e[0], e[1], e[2], e[3]);
      *(float4*)&e_s[tq] = ev;
      *(float4*)&ws[WS_EN + b * TT + t0 + tq] = ev;
    }
    float mq = fmaxf(fmaxf(e[0], e[1]), fmaxf(e[2], e[3]));
    float mn = fmaxf(om, mq);
    os = os * __expf(om - mn) + __expf(e[0] - mn) + __expf(e[1] - mn) +
         __expf(e[2] - mn) + __expf(e[3] - mn);
    om = mn;
  }

  if (lane == 0) { sm[wave] = om; ss[wave] = os; }
  __syncthreads();
  if (tid == 0) {
    const float mb = fmaxf(fmaxf(sm[0], sm[1]), fmaxf(sm[2], sm[3]));
    const float sb = ss[0] * __expf(sm[0] - mb) + ss[1] * __expf(sm[1] - mb) +
                     ss[2] * __expf(sm[2] - mb) + ss[3] * __expf(sm[3] - mb);
    float* st = ws + WS_ST + (b * 16 + chunk) * 2;
    st[0] = mb;
    st[1] = sb;
    mb_s = mb;
  }
  __syncthreads();
  if (tid < 128) w_chunk[tid] = __expf(e_s[tid] - mb_s);
  __syncthreads();

  // Phase B: stream this chunk's 128 enc rows (256 KB), weighted accumulate.
  const float4* enc4 = (const float4*)(enc + ((size_t)b * TT + t0) * EE);
  const int tp = tid >> 7;   // 0/1: row parity
  const int e4 = tid & 127;  // float4 column
  float4 acc0 = {0.f, 0.f, 0.f, 0.f}, acc1 = {0.f, 0.f, 0.f, 0.f};
#pragma unroll 8
  for (int i = 0; i < 64; ++i) {
    const int t = tp + 2 * i;
    const float w = w_chunk[t];
    const float4 v = enc4[(size_t)t * 128 + e4];
    if (i & 1) {
      acc1.x = fmaf(w, v.x, acc1.x); acc1.y = fmaf(w, v.y, acc1.y);
      acc1.z = fmaf(w, v.z, acc1.z); acc1.w = fmaf(w, v.w, acc1.w);
    } else {
      acc0.x = fmaf(w, v.x, acc0.x); acc0.y = fmaf(w, v.y, acc0.y);
      acc0.z = fmaf(w, v.z, acc0.z); acc0.w = fmaf(w, v.w, acc0.w);
    }
  }
  acc0.x += acc1.x; acc0.y += acc1.y; acc0.z += acc1.z; acc0.w += acc1.w;
  if (tp == 1) acc_s[e4] = acc0;
  __syncthreads();
  if (tp == 0) {
    const float4 o = acc_s[e4];
    acc0.x += o.x; acc0.y += o.y; acc0.z += o.z; acc0.w += o.w;
    ((float4*)(ws + WS_PART))[(size_t)(b * 16 + chunk) * 128 + e4] = acc0;
  }
}

// ---------------------------------------------------------------------------
// k2_combine: per b: global (m, S) from 16 chunk stats; weights from raw
// energies; ctx = sum_c exp(m_c - m) * partial_c / S (fixed order). 64 blocks.
// ---------------------------------------------------------------------------
__global__ __launch_bounds__(256) void k2_combine(const float* __restrict__ ws,
                                                  float* __restrict__ wts,
                                                  float* __restrict__ ctx) {
  const int b = blockIdx.x;
  const int tid = threadIdx.x;

  const float* st = ws + WS_ST + b * 32;
  float mb = -3.4e38f;
#pragma unroll
  for (int c = 0; c < 16; ++c) mb = fmaxf(mb, st[2 * c]);
  float S = 0.f;
#pragma unroll
  for (int c = 0; c < 16; ++c) S += st[2 * c + 1] * __expf(st[2 * c] - mb);
  const float inv = 1.f / S;

  __shared__ float esc[16];
  if (tid < 16) esc[tid] = __expf(st[2 * tid] - mb) * inv;
  __syncthreads();

  // weights: 2048 per b
  const float4* en4 = (const float4*)(ws + WS_EN + (size_t)b * TT);
  float4* w4 = (float4*)(wts + (size_t)b * TT);
#pragma unroll
  for (int j = 0; j < 2; ++j) {
    const float4 e = en4[tid * 2 + j];
    float4 w;
    w.x = __expf(e.x - mb) * inv;
    w.y = __expf(e.y - mb) * inv;
    w.z = __expf(e.z - mb) * inv;
    w.w = __expf(e.w - mb) * inv;
    w4[tid * 2 + j] = w;
  }

  // ctx: 512 per b; thread owns float2 column
  const float2* p2 = (const float2*)(ws + WS_PART) + (size_t)b * 16 * 256 + tid;
  float2 s = {0.f, 0.f};
#pragma unroll
  for (int c = 0; c < 16; ++c) {
    const float2 v = p2[c * 256];
    s.x = fmaf(esc[c], v.x, s.x);
    s.y = fmaf(esc[c], v.y, s.y);
  }
  ((float2*)ctx)[b * 256 + tid] = s;
}

// ---------------------------------------------------------------------------
extern "C" void kernel_launch(void* const* d_in, const int* in_sizes, int n_in,
                              void* d_out, int out_size, void* d_ws, size_t ws_size,
                              hipStream_t stream) {
  const float* enc  = (const float*)d_in[0];  // [B,T,E]
  const float* pe   = (const float*)d_in[1];  // [B,T,H]
  const float* lstm = (const float*)d_in[2];  // [B,1,DL]
  const float* awc  = (const float*)d_in[3];  // [B,T]
  const float* Wl   = (const float*)d_in[4];  // [H,DL]
  const float* cw   = (const float*)d_in[5];  // [CC,1,K]
  const float* Wloc = (const float*)d_in[6];  // [H,CC]
  const float* We   = (const float*)d_in[7];  // [1,H]

  float* out = (float*)d_out;
  float* ctx = out;            // [B,E]
  float* wts = out + BB * EE;  // [B,T]
  float* ws = (float*)d_ws;

  k0_prep<<<2049, 256, 0, stream>>>(lstm, Wl, cw, Wloc, ws);
  k1_fused<<<dim3(16, BB), 256, 0, stream>>>(pe, awc, We, enc, ws);
  k2_combine<<<BB, 256, 0, stream>>>(ws, wts, ctx);
}